// Round 6
// baseline (184.205 us; speedup 1.0000x reference)
//
#include <hip/hip_runtime.h>
#include <hip/hip_bf16.h>

#define NEG_SLOPE 0.2f

constexpr int B = 4, LQ = 1024, LK = 1024, D = 512, H = 8, HD = 64;

typedef __attribute__((ext_vector_type(8))) short bf16x8;
typedef __attribute__((ext_vector_type(4))) float f32x4;

static __device__ __forceinline__ ushort f2bf(float x) {
  return __builtin_bit_cast(ushort, __float2bfloat16(x));
}
static __device__ __forceinline__ float bf2f(ushort u) {
  return __bfloat162float(__builtin_bit_cast(__hip_bfloat16, u));
}

// ---------------------------------------------------------------------------
// Kernel 1: w_q[h][j] = sum_d a[0,h,d] * W[h*HD+d][j]; w_k likewise with a_k.
// ---------------------------------------------------------------------------
__global__ void prep_wqwk(const float* __restrict__ W, const float* __restrict__ a,
                          float* __restrict__ wq, float* __restrict__ wk) {
  int tid = blockIdx.x * blockDim.x + threadIdx.x;  // 0..4095
  int h = tid >> 9, j = tid & 511;
  const float* aq = a + h * 2 * HD;
  const float* ak = aq + HD;
  float accq = 0.f, acck = 0.f;
#pragma unroll 8
  for (int d = 0; d < HD; ++d) {
    float w = W[(size_t)(h * HD + d) * D + j];
    accq = fmaf(aq[d], w, accq);
    acck = fmaf(ak[d], w, acck);
  }
  wq[tid] = accq;
  wk[tid] = acck;
}

// ---------------------------------------------------------------------------
// Kernel 2 (fused): blocks [0,2304): cvt_split value/W -> bf16 hi/lo
//                   blocks [2304,2560): bit-pack mask via ballot
//                   blocks [2560,4608): sqsk row-dot products (needs wq/wk)
// All three parts are mutually independent; wq/wk ready via stream order.
// ---------------------------------------------------------------------------
__global__ __launch_bounds__(256) void fused_aux(
    const float* __restrict__ query, const float* __restrict__ key,
    const float* __restrict__ value, const int* __restrict__ mask,
    const float* __restrict__ W,
    const float* __restrict__ wq, const float* __restrict__ wk,
    ushort* __restrict__ val_hi, ushort* __restrict__ val_lo,
    ushort* __restrict__ w_hi, ushort* __restrict__ w_lo,
    unsigned int* __restrict__ mbits,
    float* __restrict__ sq, float* __restrict__ sk) {
  int blk = blockIdx.x, tid = threadIdx.x;
  if (blk < 2304) {
    // ---- cvt_split: idx in [0, 589824) covers VAL4+W4 exactly ----
    constexpr int VAL4 = B * LK * D / 4;  // 524288
    int idx = blk * 256 + tid;
    const float* src;
    ushort *dhi, *dlo;
    int off;
    if (idx < VAL4) { src = value; dhi = val_hi; dlo = val_lo; off = idx; }
    else           { src = W;     dhi = w_hi;   dlo = w_lo;   off = idx - VAL4; }
    float4 x = ((const float4*)src)[off];
    float xs[4] = {x.x, x.y, x.z, x.w};
    ushort hs[4], ls[4];
#pragma unroll
    for (int i = 0; i < 4; ++i) {
      hs[i] = f2bf(xs[i]);
      ls[i] = f2bf(xs[i] - bf2f(hs[i]));
    }
    ((ushort4*)dhi)[off] = make_ushort4(hs[0], hs[1], hs[2], hs[3]);
    ((ushort4*)dlo)[off] = make_ushort4(ls[0], ls[1], ls[2], ls[3]);
  } else if (blk < 2560) {
    // ---- maskbits ----
    int gw = ((blk - 2304) * 256 + tid) >> 6;  // 0..1023
    int lane = tid & 63;
#pragma unroll 4
    for (int it = 0; it < 64; ++it) {
      int wv = gw + it * 1024;  // 0..65535
      int mv = mask[(size_t)wv * 64 + lane];
      unsigned long long bal = __ballot(mv != 0);
      if (lane == 0) *(unsigned long long*)&mbits[wv * 2] = bal;
    }
  } else {
    // ---- sqsk: one wave per row ----
    int gw = ((blk - 2560) * 256 + tid) >> 6;  // 0..8191
    int lane = tid & 63;
    bool isK = gw >= B * LQ;
    int row = isK ? gw - B * LQ : gw;
    const float* x = (isK ? key : query) + (size_t)row * D + lane * 8;
    const float* wbase = isK ? wk : wq;
    float4 x0 = *(const float4*)x;
    float4 x1 = *(const float4*)(x + 4);
    float acc[H];
#pragma unroll
    for (int h = 0; h < H; ++h) {
      const float* w = wbase + h * D + lane * 8;
      float4 w0 = *(const float4*)w;
      float4 w1 = *(const float4*)(w + 4);
      acc[h] = x0.x * w0.x + x0.y * w0.y + x0.z * w0.z + x0.w * w0.w +
               x1.x * w1.x + x1.y * w1.y + x1.z * w1.z + x1.w * w1.w;
    }
#pragma unroll
    for (int off = 32; off > 0; off >>= 1) {
#pragma unroll
      for (int h = 0; h < H; ++h) acc[h] += __shfl_xor(acc[h], off, 64);
    }
    if (lane == 0) {
      int b = row >> 10, pos = row & 1023;
      float* dst = isK ? sk : sq;
#pragma unroll
      for (int h = 0; h < H; ++h) dst[((size_t)(b * H + h) << 10) + pos] = acc[h];
    }
  }
}

// ---------------------------------------------------------------------------
// Kernel 3: V = value @ W.T via split-bf16 MFMA (3-term), writing transposed
// bf16 hi/lo: vt[(b*H+h)*64+dd][k].  64x64 tile, 4 waves, BK=64, T14 pipeline
// (load next tile to regs before compute, write to LDS after barrier).
// ---------------------------------------------------------------------------
__global__ __launch_bounds__(256) void vproj_mfma(
    const ushort* __restrict__ val_hi, const ushort* __restrict__ val_lo,
    const ushort* __restrict__ w_hi, const ushort* __restrict__ w_lo,
    ushort* __restrict__ vt_hi, ushort* __restrict__ vt_lo) {
  // 72-ushort stride = 144B = 36 words; 36 mod 32 = 4 -> rows spread over all
  // bank-quads, per-bank load balanced for the 16-row fragment reads.
  __shared__ ushort as_hi[64][72], as_lo[64][72], bs_hi[64][72], bs_lo[64][72];
  int r0 = blockIdx.x * 64, c0 = blockIdx.y * 64;
  int tid = threadIdx.x, w = tid >> 6, lane = tid & 63;
  int wr = w >> 1, wc = w & 1;
  int ln15 = lane & 15, kg = lane >> 4;
  f32x4 acc[2][2] = {};
  int srow = tid >> 2, scol = (tid & 3) * 16;
  const size_t arow = (size_t)(r0 + srow) * D;
  const size_t brow = (size_t)(c0 + srow) * D;
  float4 ra0, ra1, rb0, rb1, rc0, rc1, rd0, rd1;
#define VLOAD(k0)                                                      \
  do {                                                                 \
    ra0 = *(const float4*)&val_hi[arow + (k0) + scol];                 \
    ra1 = *(const float4*)&val_hi[arow + (k0) + scol + 8];             \
    rb0 = *(const float4*)&val_lo[arow + (k0) + scol];                 \
    rb1 = *(const float4*)&val_lo[arow + (k0) + scol + 8];             \
    rc0 = *(const float4*)&w_hi[brow + (k0) + scol];                   \
    rc1 = *(const float4*)&w_hi[brow + (k0) + scol + 8];               \
    rd0 = *(const float4*)&w_lo[brow + (k0) + scol];                   \
    rd1 = *(const float4*)&w_lo[brow + (k0) + scol + 8];               \
  } while (0)
#define VSTORE()                                                       \
  do {                                                                 \
    *(float4*)&as_hi[srow][scol] = ra0;                                \
    *(float4*)&as_hi[srow][scol + 8] = ra1;                            \
    *(float4*)&as_lo[srow][scol] = rb0;                                \
    *(float4*)&as_lo[srow][scol + 8] = rb1;                            \
    *(float4*)&bs_hi[srow][scol] = rc0;                                \
    *(float4*)&bs_hi[srow][scol + 8] = rc1;                            \
    *(float4*)&bs_lo[srow][scol] = rd0;                                \
    *(float4*)&bs_lo[srow][scol + 8] = rd1;                            \
  } while (0)
  VLOAD(0);
  VSTORE();
  __syncthreads();
  for (int kt = 0; kt < 8; ++kt) {
    if (kt < 7) VLOAD((kt + 1) * 64);
#pragma unroll
    for (int ks2 = 0; ks2 < 2; ++ks2) {
      bf16x8 ah[2], al[2], bh[2], bl[2];
#pragma unroll
      for (int f = 0; f < 2; ++f) {
        int ra = wr * 32 + f * 16 + ln15;
        ah[f] = *(const bf16x8*)&as_hi[ra][ks2 * 32 + kg * 8];
        al[f] = *(const bf16x8*)&as_lo[ra][ks2 * 32 + kg * 8];
        int rb = wc * 32 + f * 16 + ln15;
        bh[f] = *(const bf16x8*)&bs_hi[rb][ks2 * 32 + kg * 8];
        bl[f] = *(const bf16x8*)&bs_lo[rb][ks2 * 32 + kg * 8];
      }
#pragma unroll
      for (int fm = 0; fm < 2; ++fm)
#pragma unroll
        for (int fn = 0; fn < 2; ++fn) {
          acc[fm][fn] = __builtin_amdgcn_mfma_f32_16x16x32_bf16(ah[fm], bh[fn], acc[fm][fn], 0, 0, 0);
          acc[fm][fn] = __builtin_amdgcn_mfma_f32_16x16x32_bf16(al[fm], bh[fn], acc[fm][fn], 0, 0, 0);
          acc[fm][fn] = __builtin_amdgcn_mfma_f32_16x16x32_bf16(ah[fm], bl[fn], acc[fm][fn], 0, 0, 0);
        }
    }
    __syncthreads();
    if (kt < 7) {
      VSTORE();
      __syncthreads();
    }
  }
#undef VLOAD
#undef VSTORE
#pragma unroll
  for (int fm = 0; fm < 2; ++fm)
#pragma unroll
    for (int fn = 0; fn < 2; ++fn) {
      int rrow = r0 + wr * 32 + fm * 16 + (lane >> 4) * 4;  // 4 consecutive k
      int col = c0 + wc * 32 + fn * 16 + ln15;
      int b = rrow >> 10, k = rrow & 1023;
      int h = col >> 6, dd = col & 63;
      size_t base = ((size_t)((b * H + h) * HD + dd) << 10) + k;
      ushort hv[4], lv[4];
#pragma unroll
      for (int r = 0; r < 4; ++r) {
        float v = acc[fm][fn][r];
        hv[r] = f2bf(v);
        lv[r] = f2bf(v - bf2f(hv[r]));
      }
      *(ushort4*)&vt_hi[base] = make_ushort4(hv[0], hv[1], hv[2], hv[3]);
      *(ushort4*)&vt_lo[base] = make_ushort4(lv[0], lv[1], lv[2], lv[3]);
    }
}

// ---------------------------------------------------------------------------
// Kernel 4: attention. Grid (B*H, LQ/64); 4 waves, each a 16-q strip.
// P generated in A-fragment registers; PV via 3-term split-bf16 MFMA;
// constant-shift softmax exp(f-8). T14 pipeline: next V-tile loaded to regs
// before the compute phase, written to LDS after the post-compute barrier.
// ---------------------------------------------------------------------------
__global__ __launch_bounds__(256) void attn_mfma(
    const float* __restrict__ sq, const float* __restrict__ sk,
    const unsigned int* __restrict__ mbits,
    const ushort* __restrict__ vt_hi, const ushort* __restrict__ vt_lo,
    float* __restrict__ out) {
  __shared__ float sks[LK];
  __shared__ ushort vhs[64][136], vls[64][136];  // 272B stride: bank-balanced
  __shared__ float linv_s[4][16];
  int bh = blockIdx.x, b = bh >> 3, h = bh & 7;
  int q0 = blockIdx.y * 64;
  int tid = threadIdx.x, w = tid >> 6, lane = tid & 63;
  int ln15 = lane & 15, kg = lane >> 4;
  int qs = q0 + w * 16 + ln15;  // this lane's q row (A-frag m index)
#pragma unroll
  for (int i = 0; i < 4; ++i) sks[i * 256 + tid] = sk[((size_t)bh << 10) + i * 256 + tid];
  float sqv = sq[((size_t)bh << 10) + qs];
  const unsigned int* mrow = mbits + ((size_t)(b << 10) + qs) * (LK / 32);
  const ushort* vhbase = vt_hi + (((size_t)bh * HD) << 10);
  const ushort* vlbase = vt_lo + (((size_t)bh * HD) << 10);
  int sdb = tid >> 4, sch = (tid & 15) * 8;
  float4 rh[4], rl[4];
#define ALOAD(k0)                                                            \
  {                                                                          \
    _Pragma("unroll") for (int c = 0; c < 4; ++c) {                          \
      int d = c * 16 + sdb;                                                  \
      rh[c] = *(const float4*)&vhbase[((size_t)d << 10) + (k0) + sch];       \
      rl[c] = *(const float4*)&vlbase[((size_t)d << 10) + (k0) + sch];       \
    }                                                                        \
  }
#define ASTORE()                                                             \
  {                                                                          \
    _Pragma("unroll") for (int c = 0; c < 4; ++c) {                          \
      int d = c * 16 + sdb;                                                  \
      *(float4*)&vhs[d][sch] = rh[c];                                        \
      *(float4*)&vls[d][sch] = rl[c];                                        \
    }                                                                        \
  }
  ALOAD(0);
  ASTORE();
  __syncthreads();  // covers sks staging too
  f32x4 acc[4] = {};
  float lsum = 0.f;
  for (int tile = 0; tile < 8; ++tile) {
    if (tile < 7) ALOAD((tile + 1) * 128);
#pragma unroll
    for (int ks = 0; ks < 4; ++ks) {
      int kb = tile * 128 + ks * 32;
      unsigned int wb = mrow[kb >> 5];
      float skv[8];
      *(float4*)&skv[0] = *(const float4*)&sks[kb + kg * 8];
      *(float4*)&skv[4] = *(const float4*)&sks[kb + kg * 8 + 4];
      bf16x8 phi, plo;
#pragma unroll
      for (int i = 0; i < 8; ++i) {
        float s = sqv + skv[i];
        float f = fmaxf(s, NEG_SLOPE * s);
        float p = ((wb >> (kg * 8 + i)) & 1u) ? __expf(f - 8.0f) : 0.f;
        lsum += p;
        ushort hb = f2bf(p);
        phi[i] = (short)hb;
        plo[i] = (short)f2bf(p - bf2f(hb));
      }
#pragma unroll
      for (int df = 0; df < 4; ++df) {
        int drow = df * 16 + ln15;
        bf16x8 bhv = *(const bf16x8*)&vhs[drow][ks * 32 + kg * 8];
        bf16x8 blv = *(const bf16x8*)&vls[drow][ks * 32 + kg * 8];
        acc[df] = __builtin_amdgcn_mfma_f32_16x16x32_bf16(phi, bhv, acc[df], 0, 0, 0);
        acc[df] = __builtin_amdgcn_mfma_f32_16x16x32_bf16(plo, bhv, acc[df], 0, 0, 0);
        acc[df] = __builtin_amdgcn_mfma_f32_16x16x32_bf16(phi, blv, acc[df], 0, 0, 0);
      }
    }
    __syncthreads();
    if (tile < 7) {
      ASTORE();
      __syncthreads();
    }
  }
#undef ALOAD
#undef ASTORE
  lsum += __shfl_xor(lsum, 16, 64);
  lsum += __shfl_xor(lsum, 32, 64);
  if (lane < 16) linv_s[w][ln15] = (lsum > 0.f) ? 1.f / lsum : 0.f;
  __syncthreads();
#pragma unroll
  for (int df = 0; df < 4; ++df) {
#pragma unroll
    for (int r = 0; r < 4; ++r) {
      int qrow = q0 + w * 16 + (lane >> 4) * 4 + r;  // verified C layout (m89)
      float inv = linv_s[w][(lane >> 4) * 4 + r];
      int col = h * HD + df * 16 + ln15;
      out[((size_t)(b << 10) + qrow) * D + col] = acc[df][r] * inv;
    }
  }
}

// ---------------------------------------------------------------------------
extern "C" void kernel_launch(void* const* d_in, const int* in_sizes, int n_in,
                              void* d_out, int out_size, void* d_ws, size_t ws_size,
                              hipStream_t stream) {
  const float* query = (const float*)d_in[0];
  const float* key   = (const float*)d_in[1];
  const float* value = (const float*)d_in[2];
  const int*   mask  = (const int*)d_in[3];
  const float* W     = (const float*)d_in[4];
  const float* a     = (const float*)d_in[5];
  float* out = (float*)d_out;

  char* ws = (char*)d_ws;
  float* wq = (float*)ws;                    ws += 4096 * 4;
  float* wk = (float*)ws;                    ws += 4096 * 4;
  float* sq = (float*)ws;                    ws += 32768 * 4;
  float* sk = (float*)ws;                    ws += 32768 * 4;
  ushort* val_hi = (ushort*)ws;              ws += (size_t)B * LK * D * 2;
  ushort* val_lo = (ushort*)ws;              ws += (size_t)B * LK * D * 2;
  ushort* w_hi = (ushort*)ws;                ws += (size_t)D * D * 2;
  ushort* w_lo = (ushort*)ws;                ws += (size_t)D * D * 2;
  ushort* vt_hi = (ushort*)ws;               ws += (size_t)B * H * HD * LK * 2;
  ushort* vt_lo = (ushort*)ws;               ws += (size_t)B * H * HD * LK * 2;
  unsigned int* mbits = (unsigned int*)ws;   ws += (size_t)B * LQ * LK / 32 * 4;

  prep_wqwk<<<dim3(16), dim3(256), 0, stream>>>(W, a, wq, wk);
  fused_aux<<<dim3(4608), dim3(256), 0, stream>>>(
      query, key, value, mask, W, wq, wk,
      val_hi, val_lo, w_hi, w_lo, mbits, sq, sk);
  vproj_mfma<<<dim3(B * LK / 64, D / 64), dim3(256), 0, stream>>>(
      val_hi, val_lo, w_hi, w_lo, vt_hi, vt_lo);
  attn_mfma<<<dim3(B * H, LQ / 64), dim3(256), 0, stream>>>(
      sq, sk, mbits, vt_hi, vt_lo, out);
}